// Round 13
// baseline (246.750 us; speedup 1.0000x reference)
//
#include <hip/hip_runtime.h>

#define NM_ 1500000
#define NT_ 100000
#define NF_ 1500000
#define NTOT (NM_ + NT_ + NF_)
#define NBY_ 1024
#define TDv 0.9f

#define NB_  512          /* binning grid blocks */
#define BT_  1024         /* binning threads/block */
#define NIT  6            /* nodes cached per thread: 6*512*1024 >= NTOT */
#define SHY_ 4
#define TSY_ 16
#define NTILY_ 64                 /* y-tiles */
#define NTILES_ 2048              /* 32 x-tiles x 64 y-tiles (32x16 bins) */
#define CAP2_ 1536u               /* 2x2-movable bucket (mean ~1140, +9 sigma) */
#define CAP3_ 768u                /* 3x3-movable bucket (mean ~490, +11 sigma) */
#define CAPF_ 256u                /* fixed-rect bucket  (mean ~115, +13 sigma) */
#define QS 0.0009765625f          /* 1/1024 */
#define FXS 65536.0f              /* LDS fixed-point scale (2^16) */
#define FXSI 1.52587890625e-5f    /* 2^-16 */

// universal 8B item: tile-local fixed point
// w0 = xq(u6.10)<<16 | yq(u6.10)   (coords offset by +32; range [-32,32))
// w1 = sxq(u5.10)<<16 | syq(u5.10)
__device__ inline uint2 pack_item(float xl, float yl, float sx, float sy) {
    unsigned xq = min((unsigned)__builtin_rintf((xl + 32.0f) * 1024.0f), 65535u);
    unsigned yq = min((unsigned)__builtin_rintf((yl + 32.0f) * 1024.0f), 65535u);
    unsigned sxq = (unsigned)__builtin_rintf(sx * 1024.0f);
    unsigned syq = (unsigned)__builtin_rintf(sy * 1024.0f);
    uint2 r; r.x = (xq << 16) | yq; r.y = (sxq << 16) | syq; return r;
}

// branchless NxN movable scatter (N=2 for span<=1 items, N=3 otherwise)
template<int N>
__device__ inline void mov_nxn(uint2 v, unsigned* sm) {
    float xl = (float)(v.x >> 16) * QS - 32.0f;
    float yl = (float)(v.x & 0xffffu) * QS - 32.0f;
    float sx = (float)(v.y >> 16) * QS;
    float sy = (float)(v.y & 0xffffu) * QS;
    float xh = xl + sx, yh = yl + sy;
    int bx0 = (int)floorf(xl), by0 = (int)floorf(yl);
    #pragma unroll
    for (int dx = 0; dx < N; ++dx) {
        int bx = bx0 + dx;
        float ox = fmaxf(fminf(xh, (float)(bx + 1)) - fmaxf(xl, (float)bx), 0.0f) * FXS;
        bool okx = ((unsigned)bx < 32u);
        int bxc = min(max(bx, 0), 31);
        #pragma unroll
        for (int dy = 0; dy < N; ++dy) {
            int by = by0 + dy;
            float oy = fmaxf(fminf(yh, (float)(by + 1)) - fmaxf(yl, (float)by), 0.0f);
            float w = (okx && ((unsigned)by < 16u)) ? ox * oy : 0.0f;
            int byc = min(max(by, 0), 15);
            atomicAdd(&sm[(bxc << 4) + byc], (unsigned)__float2uint_rn(w));
        }
    }
}

// fixed rect via separable difference maps: <=16 point adds, O(1) per rect.
__device__ inline void fix_rect_diff(uint2 v, unsigned* S, unsigned* U,
                                     unsigned* V, unsigned* W) {
    float xl = (float)(v.x >> 16) * QS - 32.0f;
    float yl = (float)(v.x & 0xffffu) * QS - 32.0f;
    float sx = (float)(v.y >> 16) * QS;
    float sy = (float)(v.y & 0xffffu) * QS;
    float xh = xl + sx, yh = yl + sy;
    int xlo = (int)floorf(xl), xhi = (int)floorf(xh);
    int ylo = (int)floorf(yl), yhi = (int)floorf(yh);
    float ax = fminf(xh, (float)(xlo + 1)) - xl;
    float bx = xh - (float)xhi;
    float ay = fminf(yh, (float)(ylo + 1)) - yl;
    float by = yh - (float)yhi;
    int xs = max(xlo + 1, 0), xe = min(xhi - 1, 31);
    int ys = max(ylo + 1, 0), ye = min(yhi - 1, 15);
    bool runx = (xs <= xe), runy = (ys <= ye);
    bool c_xlo = ((unsigned)xlo < 32u), c_xhi = ((unsigned)xhi < 32u);
    bool c_ylo = ((unsigned)ylo < 16u), c_yhi = ((unsigned)yhi < 16u);
    const float SC = TDv * FXS;
    if (c_xlo && c_ylo) atomicAdd(&S[(xlo << 4) + ylo], (unsigned)__float2int_rn(ax * ay * SC));
    if (c_xlo && c_yhi) atomicAdd(&S[(xlo << 4) + yhi], (unsigned)__float2int_rn(ax * by * SC));
    if (c_xhi && c_ylo) atomicAdd(&S[(xhi << 4) + ylo], (unsigned)__float2int_rn(bx * ay * SC));
    if (c_xhi && c_yhi) atomicAdd(&S[(xhi << 4) + yhi], (unsigned)__float2int_rn(bx * by * SC));
    if (runy) {
        int iax = __float2int_rn(ax * SC), ibx = __float2int_rn(bx * SC);
        if (c_xlo) {
            atomicAdd(&U[(xlo << 4) + ys], (unsigned)iax);
            if (ye < 15) atomicAdd(&U[(xlo << 4) + ye + 1], (unsigned)(-iax));
        }
        if (c_xhi) {
            atomicAdd(&U[(xhi << 4) + ys], (unsigned)ibx);
            if (ye < 15) atomicAdd(&U[(xhi << 4) + ye + 1], (unsigned)(-ibx));
        }
    }
    if (runx) {
        int iay = __float2int_rn(ay * SC), iby = __float2int_rn(by * SC);
        if (c_ylo) {
            atomicAdd(&V[(xs << 4) + ylo], (unsigned)iay);
            if (xe < 31) atomicAdd(&V[((xe + 1) << 4) + ylo], (unsigned)(-iay));
        }
        if (c_yhi) {
            atomicAdd(&V[(xs << 4) + yhi], (unsigned)iby);
            if (xe < 31) atomicAdd(&V[((xe + 1) << 4) + yhi], (unsigned)(-iby));
        }
    }
    if (runx && runy) {
        const int iSC = 58982;   /* round(TDv * FXS) */
        atomicAdd(&W[(xs << 4) + ys], (unsigned)iSC);
        if (ye < 15) atomicAdd(&W[(xs << 4) + ye + 1], (unsigned)(-iSC));
        if (xe < 31) {
            atomicAdd(&W[((xe + 1) << 4) + ys], (unsigned)(-iSC));
            if (ye < 15) atomicAdd(&W[((xe + 1) << 4) + ye + 1], (unsigned)iSC);
        }
    }
}

// ============== fused binning: 3 item classes (2x2 / 3x3 / fixed) ===========
__global__ __launch_bounds__(BT_) void
bin_k(const float* __restrict__ xs, const float* __restrict__ ys,
      const float* __restrict__ sxs, const float* __restrict__ sys,
      unsigned* __restrict__ g2, unsigned* __restrict__ g3, unsigned* __restrict__ gF,
      uint2* __restrict__ it2, uint2* __restrict__ it3, uint2* __restrict__ itF) {
    __shared__ unsigned lh2[NTILES_], lh3[NTILES_], lhF[NTILES_];
    __shared__ unsigned c2[NTILES_], c3[NTILES_], cF[NTILES_];
    for (int j = threadIdx.x; j < NTILES_; j += BT_) { lh2[j] = 0u; lh3[j] = 0u; lhF[j] = 0u; }
    __syncthreads();
    int t0 = blockIdx.x * BT_ + threadIdx.x;
    float cx[NIT], cy[NIT], csx[NIT], csy[NIT];
    bool val[NIT];
    int cls[NIT];   // 0 = 2x2 movable, 1 = 3x3 movable, 2 = fixed
    #pragma unroll
    for (int k = 0; k < NIT; ++k) {
        int i = t0 + k * (NB_ * BT_);
        val[k] = (i < NTOT);
        int ii = val[k] ? i : 0;
        float xi = xs[ii], yi = ys[ii], sxi = sxs[ii], syi = sys[ii];
        cx[k] = xi; cy[k] = yi; csx[k] = sxi; csy[k] = syi;
        bool fx = (i >= NM_) && (i < NM_ + NT_);
        int spx = (int)(xi + sxi) - (int)xi;
        int spy = (int)(yi + syi) - (int)yi;
        cls[k] = fx ? 2 : ((spx <= 1 && spy <= 1) ? 0 : 1);
    }
    // phase 1: per-tile LDS histogram per class
    #pragma unroll
    for (int k = 0; k < NIT; ++k) if (val[k]) {
        int txa = (int)cx[k] >> 5, txb = (int)(cx[k] + csx[k]) >> 5;
        int tya = (int)cy[k] >> SHY_, tyb = (int)(cy[k] + csy[k]) >> SHY_;
        unsigned* lh = (cls[k] == 0) ? lh2 : (cls[k] == 1) ? lh3 : lhF;
        for (int tx = txa; tx <= txb; ++tx)
            for (int ty = tya; ty <= tyb; ++ty) atomicAdd(&lh[tx * NTILY_ + ty], 1u);
    }
    __syncthreads();
    // block base within each tile bucket via one global bump per (tile, block)
    for (int j = threadIdx.x; j < NTILES_; j += BT_) {
        unsigned c = lh2[j];
        lh2[j] = c ? atomicAdd(&g2[j], c) : 0u;
        c2[j] = 0u;
        c = lh3[j];
        lh3[j] = c ? atomicAdd(&g3[j], c) : 0u;
        c3[j] = 0u;
        c = lhF[j];
        lhF[j] = c ? atomicAdd(&gF[j], c) : 0u;
        cF[j] = 0u;
    }
    __syncthreads();
    // phase 2: emit one 8B item per (node, tile) into its class bucket
    #pragma unroll
    for (int k = 0; k < NIT; ++k) if (val[k]) {
        float xi = cx[k], yi = cy[k], sxi = csx[k], syi = csy[k];
        int txa = (int)xi >> 5, txb = (int)(xi + sxi) >> 5;
        int tya = (int)yi >> SHY_, tyb = (int)(yi + syi) >> SHY_;
        unsigned* lh = (cls[k] == 0) ? lh2 : (cls[k] == 1) ? lh3 : lhF;
        unsigned* cc = (cls[k] == 0) ? c2 : (cls[k] == 1) ? c3 : cF;
        uint2* items = (cls[k] == 0) ? it2 : (cls[k] == 1) ? it3 : itF;
        unsigned cap = (cls[k] == 0) ? CAP2_ : (cls[k] == 1) ? CAP3_ : CAPF_;
        for (int tx = txa; tx <= txb; ++tx)
            for (int ty = tya; ty <= tyb; ++ty) {
                int tl = tx * NTILY_ + ty;
                unsigned r = lh[tl] + atomicAdd(&cc[tl], 1u);
                if (r < cap)
                    items[(size_t)tl * cap + r] =
                        pack_item(xi - (float)(tx * 32), yi - (float)(ty * TSY_), sxi, syi);
            }
    }
}

// ---------------------------------------------------------------- accum ----
__global__ __launch_bounds__(256) void
accum2_k(const unsigned* __restrict__ g2, const unsigned* __restrict__ g3,
         const unsigned* __restrict__ gF,
         const uint2* __restrict__ it2, const uint2* __restrict__ it3,
         const uint2* __restrict__ itF,
         const unsigned char* __restrict__ pm,
         float* __restrict__ stg, unsigned* __restrict__ done,
         float* __restrict__ out) {
    __shared__ unsigned sm[512], U[512], V[512], W[512];
    int t = blockIdx.x;
    int baseX = (t >> 6) * 32, baseY = (t & 63) * TSY_;
    for (int j = threadIdx.x; j < 512; j += 256) { sm[j] = 0u; U[j] = 0u; V[j] = 0u; W[j] = 0u; }
    __syncthreads();
    unsigned n2 = min(g2[t], CAP2_), n3 = min(g3[t], CAP3_), nf = min(gF[t], CAPF_);
    // phase A2: 2x2 movable items, uint4-paired loads
    {
        const uint4* p = (const uint4*)(it2 + (size_t)t * CAP2_);
        for (unsigned k = threadIdx.x * 2; k < n2; k += 512) {
            uint4 q = p[k >> 1];
            uint2 v0; v0.x = q.x; v0.y = q.y;
            mov_nxn<2>(v0, sm);
            if (k + 1 < n2) { uint2 v1; v1.x = q.z; v1.y = q.w; mov_nxn<2>(v1, sm); }
        }
    }
    // phase A3: 3x3 movable items, uint4-paired loads
    {
        const uint4* p = (const uint4*)(it3 + (size_t)t * CAP3_);
        for (unsigned k = threadIdx.x * 2; k < n3; k += 512) {
            uint4 q = p[k >> 1];
            uint2 v0; v0.x = q.x; v0.y = q.y;
            mov_nxn<3>(v0, sm);
            if (k + 1 < n3) { uint2 v1; v1.x = q.z; v1.y = q.w; mov_nxn<3>(v1, sm); }
        }
    }
    // phase B: fixed rects via difference maps
    {
        const uint2* p = itF + (size_t)t * CAPF_;
        for (unsigned k = threadIdx.x; k < nf; k += 256)
            fix_rect_diff(p[k], sm, U, V, W);
    }
    __syncthreads();
    // reconstruction pass 1: per-bx prefix along y; sm += Py(U); V += Py(W)
    if (threadIdx.x < 32) {
        int bx = threadIdx.x;
        unsigned u = 0, w = 0;
        for (int by = 0; by < 16; ++by) {
            int idx = (bx << 4) + by;
            u += U[idx]; w += W[idx];
            sm[idx] += u;
            V[idx] += w;
        }
    }
    __syncthreads();
    // pass 2: per-by prefix along x of (V + Py(W)) added into sm
    if (threadIdx.x < 16) {
        int by = threadIdx.x;
        unsigned tacc = 0;
        for (int bx = 0; bx < 32; ++bx) {
            int idx = (bx << 4) + by;
            tacc += V[idx];
            sm[idx] += tacc;
        }
    }
    __syncthreads();
    // fused mask + sum/max reduce into workspace staging
    float acc = 0.0f, mx = 0.0f;
    for (int j = threadIdx.x; j < 512; j += 256) {
        int lx = j >> SHY_, ly = j & (TSY_ - 1);
        float d = (float)sm[j] * FXSI;
        if (pm[(size_t)(baseX + lx) * NBY_ + baseY + ly]) d = TDv;
        acc += fmaxf(d - TDv, 0.0f);
        mx = fmaxf(mx, d);
    }
    int lane = threadIdx.x & 63, wv = threadIdx.x >> 6;
    for (int off2 = 32; off2 > 0; off2 >>= 1) {
        acc += __shfl_down(acc, off2, 64);
        mx = fmaxf(mx, __shfl_down(mx, off2, 64));
    }
    __shared__ float ssum[4], smax[4];
    if (lane == 0) { ssum[wv] = acc; smax[wv] = mx; }
    __syncthreads();
    if (threadIdx.x == 0) {
        float S = ssum[0], M = smax[0];
        for (int w2 = 1; w2 < 4; ++w2) { S += ssum[w2]; M = fmaxf(M, smax[w2]); }
        atomicAdd(stg, S);
        atomicMax((int*)stg + 1, __float_as_int(M));       // values >= 0
        __threadfence();                                   // stg visible before done bump
        unsigned old = atomicAdd(done, 1u);
        if (old == NTILES_ - 1u) {                         // last block: publish result
            float Sv = atomicAdd(stg, 0.0f);               // coherent read via atomic
            int Mi = atomicMax((int*)stg + 1, 0);
            out[0] = Sv;                                   // density_cost
            out[1] = __int_as_float(Mi);                   // max_density (bin_area == 1)
        }
    }
}

extern "C" void kernel_launch(void* const* d_in, const int* in_sizes, int n_in,
                              void* d_out, int out_size, void* d_ws, size_t ws_size,
                              hipStream_t stream) {
    const float* pos = (const float*)d_in[0];
    const float* xs = pos;
    const float* ys = pos + NTOT;
    const float* sxs = (const float*)d_in[1];
    const float* sys = (const float*)d_in[2];
    const unsigned char* pm = (const unsigned char*)d_in[5];
    float* out = (float*)d_out;

    // layout (one 24.6 KB memset covers header + class counters):
    float* stg = (float*)d_ws;                                   // 2 f32
    unsigned* done = (unsigned*)d_ws + 2;                        // 1 u32 (+1 pad)
    unsigned* g2 = (unsigned*)d_ws + 4;                          // 2048
    unsigned* g3 = g2 + NTILES_;                                 // 2048
    unsigned* gF = g3 + NTILES_;                                 // 2048
    uint2* it2 = (uint2*)(gF + NTILES_);                         // 24 MB (16B-aligned)
    uint2* it3 = it2 + (size_t)NTILES_ * CAP2_;                  // 12 MB
    uint2* itF = it3 + (size_t)NTILES_ * CAP3_;                  // 4 MB
    // total ~40.02 MB; ws >= 60.85 MB proven in R9.

    hipMemsetAsync(d_ws, 0, (4 + 3 * NTILES_) * sizeof(unsigned), stream);
    bin_k<<<NB_, BT_, 0, stream>>>(xs, ys, sxs, sys, g2, g3, gF, it2, it3, itF);
    accum2_k<<<NTILES_, 256, 0, stream>>>(g2, g3, gF, it2, it3, itF, pm, stg, done, out);
}

// Round 14
// 227.231 us; speedup vs baseline: 1.0859x; 1.0859x over previous
//
#include <hip/hip_runtime.h>

#define NM_ 1500000
#define NT_ 100000
#define NF_ 1500000
#define NTOT (NM_ + NT_ + NF_)
#define NBY_ 1024
#define TDv 0.9f

#define NB_  512          /* binning grid blocks */
#define BT_  1024         /* binning threads/block */
#define NIT  6            /* nodes cached per thread: 6*512*1024 >= NTOT */
#define SHY_ 4
#define TSY_ 16
#define NTILY_ 64                 /* y-tiles */
#define NTILES_ 2048              /* 32 x-tiles x 64 y-tiles (32x16 bins) */
#define CAP_M 2048u               /* movable bucket stride (mean 1619, +10 sigma) */
#define CAP_F 256u                /* fixed-rect bucket stride (mean ~115, +13 sigma) */
#define QS 0.0009765625f          /* 1/1024 */
#define FXS 65536.0f              /* LDS fixed-point scale (2^16) */
#define FXSI 1.52587890625e-5f    /* 2^-16 */

// universal 8B item: tile-local fixed point
// w0 = xq(u6.10)<<16 | yq(u6.10)   (coords offset by +32; range [-32,32))
// w1 = sxq(u5.10)<<16 | syq(u5.10)
__device__ inline uint2 pack_item(float xl, float yl, float sx, float sy) {
    unsigned xq = min((unsigned)__builtin_rintf((xl + 32.0f) * 1024.0f), 65535u);
    unsigned yq = min((unsigned)__builtin_rintf((yl + 32.0f) * 1024.0f), 65535u);
    unsigned sxq = (unsigned)__builtin_rintf(sx * 1024.0f);
    unsigned syq = (unsigned)__builtin_rintf(sy * 1024.0f);
    uint2 r; r.x = (xq << 16) | yq; r.y = (sxq << 16) | syq; return r;
}

// movable item: branchless fully-unrolled 3x3 (span <= 3x3 always).
__device__ inline void mov_3x3(uint2 v, unsigned* sm) {
    float xl = (float)(v.x >> 16) * QS - 32.0f;
    float yl = (float)(v.x & 0xffffu) * QS - 32.0f;
    float sx = (float)(v.y >> 16) * QS;
    float sy = (float)(v.y & 0xffffu) * QS;
    float xh = xl + sx, yh = yl + sy;
    int bx0 = (int)floorf(xl), by0 = (int)floorf(yl);
    #pragma unroll
    for (int dx = 0; dx < 3; ++dx) {
        int bx = bx0 + dx;
        float ox = fmaxf(fminf(xh, (float)(bx + 1)) - fmaxf(xl, (float)bx), 0.0f) * FXS;
        bool okx = ((unsigned)bx < 32u);
        int bxc = min(max(bx, 0), 31);
        #pragma unroll
        for (int dy = 0; dy < 3; ++dy) {
            int by = by0 + dy;
            float oy = fmaxf(fminf(yh, (float)(by + 1)) - fmaxf(yl, (float)by), 0.0f);
            float w = (okx && ((unsigned)by < 16u)) ? ox * oy : 0.0f;
            int byc = min(max(by, 0), 15);
            atomicAdd(&sm[(bxc << 4) + byc], (unsigned)__float2uint_rn(w));
        }
    }
}

// fixed rect via separable difference maps: <=16 point adds, O(1) per rect.
__device__ inline void fix_rect_diff(uint2 v, unsigned* S, unsigned* U,
                                     unsigned* V, unsigned* W) {
    float xl = (float)(v.x >> 16) * QS - 32.0f;
    float yl = (float)(v.x & 0xffffu) * QS - 32.0f;
    float sx = (float)(v.y >> 16) * QS;
    float sy = (float)(v.y & 0xffffu) * QS;
    float xh = xl + sx, yh = yl + sy;
    int xlo = (int)floorf(xl), xhi = (int)floorf(xh);
    int ylo = (int)floorf(yl), yhi = (int)floorf(yh);
    float ax = fminf(xh, (float)(xlo + 1)) - xl;
    float bx = xh - (float)xhi;
    float ay = fminf(yh, (float)(ylo + 1)) - yl;
    float by = yh - (float)yhi;
    int xs = max(xlo + 1, 0), xe = min(xhi - 1, 31);
    int ys = max(ylo + 1, 0), ye = min(yhi - 1, 15);
    bool runx = (xs <= xe), runy = (ys <= ye);
    bool c_xlo = ((unsigned)xlo < 32u), c_xhi = ((unsigned)xhi < 32u);
    bool c_ylo = ((unsigned)ylo < 16u), c_yhi = ((unsigned)yhi < 16u);
    const float SC = TDv * FXS;
    if (c_xlo && c_ylo) atomicAdd(&S[(xlo << 4) + ylo], (unsigned)__float2int_rn(ax * ay * SC));
    if (c_xlo && c_yhi) atomicAdd(&S[(xlo << 4) + yhi], (unsigned)__float2int_rn(ax * by * SC));
    if (c_xhi && c_ylo) atomicAdd(&S[(xhi << 4) + ylo], (unsigned)__float2int_rn(bx * ay * SC));
    if (c_xhi && c_yhi) atomicAdd(&S[(xhi << 4) + yhi], (unsigned)__float2int_rn(bx * by * SC));
    if (runy) {
        int iax = __float2int_rn(ax * SC), ibx = __float2int_rn(bx * SC);
        if (c_xlo) {
            atomicAdd(&U[(xlo << 4) + ys], (unsigned)iax);
            if (ye < 15) atomicAdd(&U[(xlo << 4) + ye + 1], (unsigned)(-iax));
        }
        if (c_xhi) {
            atomicAdd(&U[(xhi << 4) + ys], (unsigned)ibx);
            if (ye < 15) atomicAdd(&U[(xhi << 4) + ye + 1], (unsigned)(-ibx));
        }
    }
    if (runx) {
        int iay = __float2int_rn(ay * SC), iby = __float2int_rn(by * SC);
        if (c_ylo) {
            atomicAdd(&V[(xs << 4) + ylo], (unsigned)iay);
            if (xe < 31) atomicAdd(&V[((xe + 1) << 4) + ylo], (unsigned)(-iay));
        }
        if (c_yhi) {
            atomicAdd(&V[(xs << 4) + yhi], (unsigned)iby);
            if (xe < 31) atomicAdd(&V[((xe + 1) << 4) + yhi], (unsigned)(-iby));
        }
    }
    if (runx && runy) {
        const int iSC = 58982;   /* round(TDv * FXS) */
        atomicAdd(&W[(xs << 4) + ys], (unsigned)iSC);
        if (ye < 15) atomicAdd(&W[(xs << 4) + ye + 1], (unsigned)(-iSC));
        if (xe < 31) {
            atomicAdd(&W[((xe + 1) << 4) + ys], (unsigned)(-iSC));
            if (ye < 15) atomicAdd(&W[((xe + 1) << 4) + ye + 1], (unsigned)iSC);
        }
    }
}

// ============== fused binning: per-tile rect items (R12-proven) =============
__global__ __launch_bounds__(BT_) void
bin_k(const float* __restrict__ xs, const float* __restrict__ ys,
      const float* __restrict__ sxs, const float* __restrict__ sys,
      unsigned* __restrict__ gM, unsigned* __restrict__ gF,
      uint2* __restrict__ itemsM, uint2* __restrict__ itemsF) {
    __shared__ unsigned lhM[NTILES_], lhF[NTILES_];   // counts -> bucket bases
    __shared__ unsigned cM[NTILES_], cF[NTILES_];     // phase-2 cursors
    for (int j = threadIdx.x; j < NTILES_; j += BT_) { lhM[j] = 0u; lhF[j] = 0u; }
    __syncthreads();
    int t0 = blockIdx.x * BT_ + threadIdx.x;
    float cx[NIT], cy[NIT], csx[NIT], csy[NIT];
    bool val[NIT], fix[NIT];
    #pragma unroll
    for (int k = 0; k < NIT; ++k) {
        int i = t0 + k * (NB_ * BT_);
        val[k] = (i < NTOT);
        int ii = val[k] ? i : 0;
        cx[k] = xs[ii]; cy[k] = ys[ii]; csx[k] = sxs[ii]; csy[k] = sys[ii];
        fix[k] = (i >= NM_) && (i < NM_ + NT_);
    }
    // phase 1: per-tile LDS histogram
    #pragma unroll
    for (int k = 0; k < NIT; ++k) if (val[k]) {
        float xi = cx[k], yi = cy[k];
        int txa = (int)xi >> 5, txb = (int)(xi + csx[k]) >> 5;
        int tya = (int)yi >> SHY_, tyb = (int)(yi + csy[k]) >> SHY_;
        unsigned* lh = fix[k] ? lhF : lhM;
        for (int tx = txa; tx <= txb; ++tx)
            for (int ty = tya; ty <= tyb; ++ty) atomicAdd(&lh[tx * NTILY_ + ty], 1u);
    }
    __syncthreads();
    // block base within each tile bucket via one global bump per (tile, block)
    for (int j = threadIdx.x; j < NTILES_; j += BT_) {
        unsigned c = lhM[j];
        lhM[j] = c ? atomicAdd(&gM[j], c) : 0u;
        cM[j] = 0u;
        c = lhF[j];
        lhF[j] = c ? atomicAdd(&gF[j], c) : 0u;
        cF[j] = 0u;
    }
    __syncthreads();
    // phase 2: emit one 8B rect item per (node, tile)
    #pragma unroll
    for (int k = 0; k < NIT; ++k) if (val[k]) {
        float xi = cx[k], yi = cy[k], sxi = csx[k], syi = csy[k];
        int txa = (int)xi >> 5, txb = (int)(xi + sxi) >> 5;
        int tya = (int)yi >> SHY_, tyb = (int)(yi + syi) >> SHY_;
        if (fix[k]) {
            for (int tx = txa; tx <= txb; ++tx)
                for (int ty = tya; ty <= tyb; ++ty) {
                    int tl = tx * NTILY_ + ty;
                    unsigned r = lhF[tl] + atomicAdd(&cF[tl], 1u);
                    if (r < CAP_F)
                        itemsF[(size_t)tl * CAP_F + r] =
                            pack_item(xi - (float)(tx * 32), yi - (float)(ty * TSY_), sxi, syi);
                }
        } else {
            for (int tx = txa; tx <= txb; ++tx)
                for (int ty = tya; ty <= tyb; ++ty) {
                    int tl = tx * NTILY_ + ty;
                    unsigned r = lhM[tl] + atomicAdd(&cM[tl], 1u);
                    if (r < CAP_M)
                        itemsM[(size_t)tl * CAP_M + r] =
                            pack_item(xi - (float)(tx * 32), yi - (float)(ty * TSY_), sxi, syi);
                }
        }
    }
}

// ---------------------------------------------------------------- accum ----
__global__ __launch_bounds__(256) void
accum2_k(const unsigned* __restrict__ gM, const unsigned* __restrict__ gF,
         const uint2* __restrict__ itemsM, const uint2* __restrict__ itemsF,
         const unsigned char* __restrict__ pm,
         float* __restrict__ stg, unsigned* __restrict__ done,
         float* __restrict__ out) {
    __shared__ unsigned sm[512], U[512], V[512], W[512];
    int t = blockIdx.x;
    int baseX = (t >> 6) * 32, baseY = (t & 63) * TSY_;
    for (int j = threadIdx.x; j < 512; j += 256) { sm[j] = 0u; U[j] = 0u; V[j] = 0u; W[j] = 0u; }
    __syncthreads();
    unsigned nm = min(gM[t], CAP_M), nf = min(gF[t], CAP_F);
    const uint2* im = itemsM + (size_t)t * CAP_M;
    const uint2* fi = itemsF + (size_t)t * CAP_F;
    // phase A: movable rects, branchless 3x3, 2-way ILP -> sm (=S)
    for (unsigned k = threadIdx.x * 2; k < nm; k += 512) {
        uint2 v0 = im[k];
        bool h2 = (k + 1 < nm);
        uint2 v1 = h2 ? im[k + 1] : make_uint2(0u, 0u);   // (0,0) -> w=0 everywhere
        mov_3x3(v0, sm);
        mov_3x3(v1, sm);
    }
    // phase B: fixed rects, per-lane difference-map scatter (O(1) per rect)
    for (unsigned k = threadIdx.x; k < nf; k += 256)
        fix_rect_diff(fi[k], sm, U, V, W);
    __syncthreads();
    // reconstruction pass 1: per-bx prefix along y; sm += Py(U); V += Py(W)
    if (threadIdx.x < 32) {
        int bx = threadIdx.x;
        unsigned u = 0, w = 0;
        for (int by = 0; by < 16; ++by) {
            int idx = (bx << 4) + by;
            u += U[idx]; w += W[idx];
            sm[idx] += u;
            V[idx] += w;
        }
    }
    __syncthreads();
    // pass 2: per-by prefix along x of (V + Py(W)) added into sm
    if (threadIdx.x < 16) {
        int by = threadIdx.x;
        unsigned tacc = 0;
        for (int bx = 0; bx < 32; ++bx) {
            int idx = (bx << 4) + by;
            tacc += V[idx];
            sm[idx] += tacc;
        }
    }
    __syncthreads();
    // fused mask + sum/max reduce; publish via last-block pattern (no d_out memset)
    float acc = 0.0f, mx = 0.0f;
    for (int j = threadIdx.x; j < 512; j += 256) {
        int lx = j >> SHY_, ly = j & (TSY_ - 1);
        float d = (float)sm[j] * FXSI;
        if (pm[(size_t)(baseX + lx) * NBY_ + baseY + ly]) d = TDv;
        acc += fmaxf(d - TDv, 0.0f);
        mx = fmaxf(mx, d);
    }
    int lane = threadIdx.x & 63, wv = threadIdx.x >> 6;
    for (int off2 = 32; off2 > 0; off2 >>= 1) {
        acc += __shfl_down(acc, off2, 64);
        mx = fmaxf(mx, __shfl_down(mx, off2, 64));
    }
    __shared__ float ssum[4], smax[4];
    if (lane == 0) { ssum[wv] = acc; smax[wv] = mx; }
    __syncthreads();
    if (threadIdx.x == 0) {
        float S = ssum[0], M = smax[0];
        for (int w2 = 1; w2 < 4; ++w2) { S += ssum[w2]; M = fmaxf(M, smax[w2]); }
        atomicAdd(stg, S);
        atomicMax((int*)stg + 1, __float_as_int(M));       // values >= 0
        __threadfence();                                   // stg visible before done bump
        unsigned old = atomicAdd(done, 1u);
        if (old == NTILES_ - 1u) {                         // last block: publish result
            float Sv = atomicAdd(stg, 0.0f);               // coherent read via atomic
            int Mi = atomicMax((int*)stg + 1, 0);
            out[0] = Sv;                                   // density_cost
            out[1] = __int_as_float(Mi);                   // max_density (bin_area == 1)
        }
    }
}

extern "C" void kernel_launch(void* const* d_in, const int* in_sizes, int n_in,
                              void* d_out, int out_size, void* d_ws, size_t ws_size,
                              hipStream_t stream) {
    const float* pos = (const float*)d_in[0];
    const float* xs = pos;
    const float* ys = pos + NTOT;
    const float* sxs = (const float*)d_in[1];
    const float* sys = (const float*)d_in[2];
    const unsigned char* pm = (const unsigned char*)d_in[5];
    float* out = (float*)d_out;

    // layout (one contiguous 16.4 KB memset covers header + counters):
    float* stg = (float*)d_ws;                                   // 2 f32
    unsigned* done = (unsigned*)d_ws + 2;                        // 1 u32 (+1 pad)
    unsigned* gM = (unsigned*)d_ws + 4;                          // 2048
    unsigned* gF = gM + NTILES_;                                 // 2048
    uint2* itemsM = (uint2*)(gF + NTILES_);                      // 32 MB (16B-aligned)
    uint2* itemsF = itemsM + (size_t)NTILES_ * CAP_M;            // 4 MB
    // total ~36.02 MB; ws >= 60.85 MB proven in R9.

    hipMemsetAsync(d_ws, 0, (4 + 2 * NTILES_) * sizeof(unsigned), stream);
    bin_k<<<NB_, BT_, 0, stream>>>(xs, ys, sxs, sys, gM, gF, itemsM, itemsF);
    accum2_k<<<NTILES_, 256, 0, stream>>>(gM, gF, itemsM, itemsF, pm, stg, done, out);
}